// Round 1
// baseline (4134.019 us; speedup 1.0000x reference)
//
#include <hip/hip_runtime.h>

#define B_ 32
#define T_ 1024
#define C_ 384
#define MAXLEN_ 2048
#define NBINS_ 255   /* NB-1 = 255 bin edges */

constexpr int BM  = 16;   // output rows (t) per block
constexpr int BK  = 16;   // K-chunk staged through LDS
constexpr int PAD = 4;    // xs row padding (floats) -> kills row-stride bank alias

// Fused conv1d(K=3,SAME) + bias + relu + LayerNorm [+ scalar projection].
// GEMM view: y[row, f] = sum_{kk<1152} A[row,kk] * w[kk,f],
//   A[row, k*384+h] = x[b, t+k-1, h]  (zero-padded at t=-1, t=T)
//   w given as (3,384,384) row-major == (1152,384) row-major.
__global__ __launch_bounds__(256) void conv_ln_kernel(
    const float* __restrict__ xin,    // (B,T,384)
    const float* __restrict__ w,      // (1152,384)
    const float* __restrict__ bias,   // (384)
    const float* __restrict__ gamma,  // (384)
    const float* __restrict__ beta,   // (384)
    const float* __restrict__ wo,     // (384) or null
    const float* __restrict__ bo,     // (1)   or null
    float* __restrict__ hout,         // (B,T,384) or null
    float* __restrict__ pred,         // (B,T)     or null
    int final_flag)
{
    __shared__ float xs[BM + 2][C_ + PAD];  // rows t0-1 .. t0+BM
    __shared__ float wsm[BK][C_];

    const int tid = threadIdx.x;
    const int bi  = blockIdx.x;
    const int b   = bi >> 6;            // T/BM = 64 blocks per batch row
    const int t0  = (bi & 63) << 4;

    // ---- stage x window into LDS (float4) ----
    for (int i = tid; i < (BM + 2) * (C_ / 4); i += 256) {
        const int r  = i / 96;
        const int c4 = i % 96;
        const int t  = t0 - 1 + r;
        float4 v = make_float4(0.f, 0.f, 0.f, 0.f);
        if (t >= 0 && t < T_)
            v = *(const float4*)(xin + ((size_t)b * T_ + t) * C_ + c4 * 4);
        *(float4*)&xs[r][c4 * 4] = v;
    }

    // micro-tile: 2 rows x 12 cols per thread
    const int rg = tid >> 5;          // 0..7  -> rows rg*2, rg*2+1
    const int cg = tid & 31;          // cols cg*4 + 128*j + l  (j<3, l<4)
    const int r0 = rg * 2;

    float acc0[12], acc1[12];
#pragma unroll
    for (int j = 0; j < 12; ++j) { acc0[j] = 0.f; acc1[j] = 0.f; }

    for (int kb = 0; kb < 1152; kb += BK) {
        __syncthreads();  // (also covers initial xs staging) protect wsm reuse
        for (int i = tid; i < BK * 96; i += 256) {
            const int kk = i / 96;
            const int c4 = i % 96;
            *(float4*)&wsm[kk][c4 * 4] =
                *(const float4*)(w + (size_t)(kb + kk) * C_ + c4 * 4);
        }
        __syncthreads();

        const int k  = kb / 384;        // chunk never crosses a k boundary (384%16==0)
        const int hb = kb - k * 384;
        const float* xrow0 = &xs[r0 + k][hb];
        const float* xrow1 = &xs[r0 + 1 + k][hb];

#pragma unroll
        for (int kk2 = 0; kk2 < BK; ++kk2) {
            const float xa = xrow0[kk2];
            const float xb = xrow1[kk2];
#pragma unroll
            for (int j = 0; j < 3; ++j) {
                const float4 wv = *(const float4*)&wsm[kk2][cg * 4 + 128 * j];
                acc0[j * 4 + 0] += xa * wv.x;
                acc0[j * 4 + 1] += xa * wv.y;
                acc0[j * 4 + 2] += xa * wv.z;
                acc0[j * 4 + 3] += xa * wv.w;
                acc1[j * 4 + 0] += xb * wv.x;
                acc1[j * 4 + 1] += xb * wv.y;
                acc1[j * 4 + 2] += xb * wv.z;
                acc1[j * 4 + 3] += xb * wv.w;
            }
        }
    }

    // ---- epilogue: bias + relu, LN stats over the 384 cols of each row ----
    float s0 = 0.f, s1 = 0.f, q0 = 0.f, q1 = 0.f;
#pragma unroll
    for (int j = 0; j < 3; ++j) {
        const float4 bv = *(const float4*)(bias + cg * 4 + 128 * j);
        const float bb[4] = {bv.x, bv.y, bv.z, bv.w};
#pragma unroll
        for (int l = 0; l < 4; ++l) {
            float a = acc0[j * 4 + l] + bb[l];
            a = a > 0.f ? a : 0.f;
            acc0[j * 4 + l] = a;
            s0 += a; q0 += a * a;
            float c = acc1[j * 4 + l] + bb[l];
            c = c > 0.f ? c : 0.f;
            acc1[j * 4 + l] = c;
            s1 += c; q1 += c * c;
        }
    }
    // half-wave (32-lane) reduction: each row's partials live in lanes sharing rg
#pragma unroll
    for (int off = 1; off < 32; off <<= 1) {
        s0 += __shfl_xor(s0, off, 64);
        q0 += __shfl_xor(q0, off, 64);
        s1 += __shfl_xor(s1, off, 64);
        q1 += __shfl_xor(q1, off, 64);
    }
    const float inv = 1.0f / 384.0f;
    const float m0 = s0 * inv, m1 = s1 * inv;
    const float v0 = q0 * inv - m0 * m0;
    const float v1 = q1 * inv - m1 * m1;
    const float rs0 = rsqrtf(v0 + 1e-5f);
    const float rs1 = rsqrtf(v1 + 1e-5f);

    if (!final_flag) {
#pragma unroll
        for (int j = 0; j < 3; ++j) {
            const float4 g  = *(const float4*)(gamma + cg * 4 + 128 * j);
            const float4 be = *(const float4*)(beta  + cg * 4 + 128 * j);
            float4 o0, o1;
            o0.x = (acc0[j*4+0] - m0) * rs0 * g.x + be.x;
            o0.y = (acc0[j*4+1] - m0) * rs0 * g.y + be.y;
            o0.z = (acc0[j*4+2] - m0) * rs0 * g.z + be.z;
            o0.w = (acc0[j*4+3] - m0) * rs0 * g.w + be.w;
            o1.x = (acc1[j*4+0] - m1) * rs1 * g.x + be.x;
            o1.y = (acc1[j*4+1] - m1) * rs1 * g.y + be.y;
            o1.z = (acc1[j*4+2] - m1) * rs1 * g.z + be.z;
            o1.w = (acc1[j*4+3] - m1) * rs1 * g.w + be.w;
            *(float4*)(hout + ((size_t)b * T_ + t0 + r0)     * C_ + cg * 4 + 128 * j) = o0;
            *(float4*)(hout + ((size_t)b * T_ + t0 + r0 + 1) * C_ + cg * 4 + 128 * j) = o1;
        }
    } else {
        float p0 = 0.f, p1 = 0.f;
#pragma unroll
        for (int j = 0; j < 3; ++j) {
            const float4 g  = *(const float4*)(gamma + cg * 4 + 128 * j);
            const float4 be = *(const float4*)(beta  + cg * 4 + 128 * j);
            const float4 wv = *(const float4*)(wo    + cg * 4 + 128 * j);
            p0 += ((acc0[j*4+0] - m0) * rs0 * g.x + be.x) * wv.x;
            p0 += ((acc0[j*4+1] - m0) * rs0 * g.y + be.y) * wv.y;
            p0 += ((acc0[j*4+2] - m0) * rs0 * g.z + be.z) * wv.z;
            p0 += ((acc0[j*4+3] - m0) * rs0 * g.w + be.w) * wv.w;
            p1 += ((acc1[j*4+0] - m1) * rs1 * g.x + be.x) * wv.x;
            p1 += ((acc1[j*4+1] - m1) * rs1 * g.y + be.y) * wv.y;
            p1 += ((acc1[j*4+2] - m1) * rs1 * g.z + be.z) * wv.z;
            p1 += ((acc1[j*4+3] - m1) * rs1 * g.w + be.w) * wv.w;
        }
#pragma unroll
        for (int off = 1; off < 32; off <<= 1) {
            p0 += __shfl_xor(p0, off, 64);
            p1 += __shfl_xor(p1, off, 64);
        }
        if (cg == 0) {
            const float bb = bo[0];
            pred[(size_t)b * T_ + t0 + r0]     = p0 + bb;
            pred[(size_t)b * T_ + t0 + r0 + 1] = p1 + bb;
        }
    }
}

// xdst = xsrc + emb[searchsorted_left(bins, target)]
__global__ __launch_bounds__(256) void add_emb_kernel(
    const float* __restrict__ xsrc, const float* __restrict__ target,
    const float* __restrict__ bins, const float* __restrict__ emb,
    float* __restrict__ xdst)
{
    const int g   = blockIdx.x * 256 + threadIdx.x;  // over B*T*96 (exact)
    const int c4  = g % 96;
    const int row = g / 96;
    const float v = target[row];
    int lo = 0, hi = NBINS_;
    while (lo < hi) {
        const int mid = (lo + hi) >> 1;
        if (bins[mid] < v) lo = mid + 1; else hi = mid;
    }
    float4 xv = *(const float4*)(xsrc + (size_t)row * C_ + c4 * 4);
    const float4 ev = *(const float4*)(emb + (size_t)lo * C_ + c4 * 4);
    xv.x += ev.x; xv.y += ev.y; xv.z += ev.z; xv.w += ev.w;
    *(float4*)(xdst + (size_t)row * C_ + c4 * 4) = xv;
}

// per-batch inclusive cumsum of duration (T=1024) + mel_len (as float)
__global__ __launch_bounds__(256) void cumsum_kernel(
    const int* __restrict__ dur, int* __restrict__ csum,
    float* __restrict__ mel_len)
{
    __shared__ int part[256];
    const int b = blockIdx.x;
    const int tid = threadIdx.x;
    int l[4];
    int s = 0;
#pragma unroll
    for (int i = 0; i < 4; ++i) { l[i] = dur[b * T_ + tid * 4 + i]; s += l[i]; }
    part[tid] = s;
    __syncthreads();
    for (int off = 1; off < 256; off <<= 1) {
        int u = 0;
        if (tid >= off) u = part[tid - off];
        __syncthreads();
        part[tid] += u;
        __syncthreads();
    }
    const int incl = part[tid];
    int run = incl - s;  // exclusive prefix for this thread's 4 elems
#pragma unroll
    for (int i = 0; i < 4; ++i) {
        run += l[i];
        csum[b * T_ + tid * 4 + i] = run;
    }
    if (tid == 255) mel_len[b] = (float)incl;
}

// out[b,frame,:] = valid ? x[b, clip(searchsorted_right(csum, frame),0,1023), :] : 0
__global__ __launch_bounds__(256) void length_reg_kernel(
    const float* __restrict__ x, const int* __restrict__ csum,
    float* __restrict__ out)
{
    const int g    = blockIdx.x * 256 + threadIdx.x;  // B*2048*96 (exact)
    const int c4   = g % 96;
    const int rest = g / 96;
    const int frame = rest & (MAXLEN_ - 1);
    const int b     = rest >> 11;
    const int* cr = csum + b * T_;
    const int total = cr[T_ - 1];
    float4 v = make_float4(0.f, 0.f, 0.f, 0.f);
    if (frame < total) {
        int lo = 0, hi = T_;
        while (lo < hi) {
            const int mid = (lo + hi) >> 1;
            if (cr[mid] <= frame) lo = mid + 1; else hi = mid;
        }
        if (lo > T_ - 1) lo = T_ - 1;
        v = *(const float4*)(x + ((size_t)b * T_ + lo) * C_ + c4 * 4);
    }
    *(float4*)(out + (size_t)g * 4) = v;
}

extern "C" void kernel_launch(void* const* d_in, const int* in_sizes, int n_in,
                              void* d_out, int out_size, void* d_ws, size_t ws_size,
                              hipStream_t stream)
{
    const float* x        = (const float*)d_in[0];
    const int*   duration = (const int*)d_in[2];
    const float* P[3][10];
    for (int p = 0; p < 3; ++p)
        for (int q = 0; q < 10; ++q)
            P[p][q] = (const float*)d_in[4 + p * 10 + q];
    const float* pitch_bins    = (const float*)d_in[34];
    const float* energy_bins   = (const float*)d_in[35];
    const float* pitch_emb     = (const float*)d_in[36];
    const float* energy_emb    = (const float*)d_in[37];
    const float* pitch_target  = (const float*)d_in[38];
    const float* energy_target = (const float*)d_in[39];

    float* out_x      = (float*)d_out;                       // (B,2048,384)
    float* out_pitch  = out_x + (size_t)B_ * MAXLEN_ * C_;   // (B,T)
    float* out_energy = out_pitch + B_ * T_;
    float* out_logdur = out_energy + B_ * T_;
    float* out_mellen = out_logdur + B_ * T_;                // (B,)

    // h1 scratch lives in the x_out region (only overwritten by the final kernel)
    float* h1   = out_x;
    float* x2   = (float*)d_ws;                              // (B,T,384)
    int*   csum = (int*)(x2 + (size_t)B_ * T_ * C_);         // (B,T)

    const dim3 blk(256);
    const dim3 gConv(2048);

    // duration predictor (on original x)
    conv_ln_kernel<<<gConv, blk, 0, stream>>>(x,  P[0][0], P[0][1], P[0][2], P[0][3],
                                              nullptr, nullptr, h1, nullptr, 0);
    conv_ln_kernel<<<gConv, blk, 0, stream>>>(h1, P[0][4], P[0][5], P[0][6], P[0][7],
                                              P[0][8], P[0][9], nullptr, out_logdur, 1);
    // pitch predictor (on original x)
    conv_ln_kernel<<<gConv, blk, 0, stream>>>(x,  P[1][0], P[1][1], P[1][2], P[1][3],
                                              nullptr, nullptr, h1, nullptr, 0);
    conv_ln_kernel<<<gConv, blk, 0, stream>>>(h1, P[1][4], P[1][5], P[1][6], P[1][7],
                                              P[1][8], P[1][9], nullptr, out_pitch, 1);
    // x2 = x + pitch_emb[searchsorted(pitch_bins, pitch_target)]
    add_emb_kernel<<<12288, blk, 0, stream>>>(x, pitch_target, pitch_bins, pitch_emb, x2);
    // energy predictor (on x2)
    conv_ln_kernel<<<gConv, blk, 0, stream>>>(x2, P[2][0], P[2][1], P[2][2], P[2][3],
                                              nullptr, nullptr, h1, nullptr, 0);
    conv_ln_kernel<<<gConv, blk, 0, stream>>>(h1, P[2][4], P[2][5], P[2][6], P[2][7],
                                              P[2][8], P[2][9], nullptr, out_energy, 1);
    // x2 += energy_emb[...]  (in-place, per-element)
    add_emb_kernel<<<12288, blk, 0, stream>>>(x2, energy_target, energy_bins, energy_emb, x2);
    // cumsum + mel_len
    cumsum_kernel<<<B_, blk, 0, stream>>>(duration, csum, out_mellen);
    // length regulate -> x_out (overwrites the h1 scratch region)
    length_reg_kernel<<<24576, blk, 0, stream>>>(x2, csum, out_x);
}

// Round 2
// 715.641 us; speedup vs baseline: 5.7767x; 5.7767x over previous
//
#include <hip/hip_runtime.h>

#define B_ 32
#define T_ 1024
#define C_ 384
#define MAXLEN_ 2048
#define NBINS_ 255

typedef __attribute__((ext_vector_type(8))) short short8v;   // 8 bf16 = 4 VGPRs
typedef __attribute__((ext_vector_type(4))) float floatx4;

__device__ __forceinline__ unsigned short f2bf(float f) {
    unsigned u = __float_as_uint(f);
    u += 0x7fffu + ((u >> 16) & 1u);   // RNE
    return (unsigned short)(u >> 16);
}

__device__ __forceinline__ void async_copy16(const void* g, void* l) {
    __builtin_amdgcn_global_load_lds(
        (const __attribute__((address_space(1))) void*)g,
        (__attribute__((address_space(3))) void*)l, 16, 0, 0);
}

// ---------------------------------------------------------------------------
// Fused conv1d(K=3,SAME)+bias+relu+LayerNorm[+projection], bf16 MFMA.
// GEMM: y[row,f] = sum_k A[row,k]*B[k,f], K=1152, A = shifted x (bf16),
// B = w packed as wpk[36][384][32] (n-major, k-contiguous per 32-chunk).
// Block: 256 thr = 4 waves; tile 64 rows x 384 cols; wave owns 96 cols.
// ---------------------------------------------------------------------------
__global__ __launch_bounds__(256, 2) void conv_mfma_kernel(
    const unsigned short* __restrict__ xbf,   // (B*T,384) bf16
    const unsigned short* __restrict__ wpk,   // (36,384,32) bf16
    const float* __restrict__ bias,
    const float* __restrict__ gamma,
    const float* __restrict__ beta,
    const float* __restrict__ wo,             // (384) or null
    const float* __restrict__ bo,             // (1)   or null
    unsigned short* __restrict__ hout,        // bf16 (B*T,384) or null
    float* __restrict__ pred,                 // (B*T) or null
    int final_flag)
{
    __shared__ unsigned short slab[12288];    // 24 KB: [384 n][32 k]
    __shared__ float rsum[4][64];
    __shared__ float rsq[4][64];

    const int tid  = threadIdx.x;
    const int wave = tid >> 6;
    const int lane = tid & 63;
    const int lq   = lane >> 4;     // quad 0..3
    const int ln   = lane & 15;
    const int bi   = blockIdx.x;    // 512 blocks
    const int R0   = bi << 6;       // global row base (b*1024 + t0)
    const int b    = bi >> 4;
    const int t0   = (bi & 15) << 6;
    const int nb   = wave * 96;     // wave's column base

    floatx4 acc[24];
#pragma unroll
    for (int i = 0; i < 24; ++i) acc[i] = (floatx4){0.f, 0.f, 0.f, 0.f};

    for (int r = 0; r < 36; ++r) {
        __syncthreads();                       // previous slab fully consumed
        const unsigned short* gsrc = wpk + r * 12288;
#pragma unroll
        for (int it = 0; it < 6; ++it) {
            const int c = it * 4 + wave;       // 1 KB chunk per wave-issue
            async_copy16(gsrc + c * 512 + lane * 8, &slab[c * 512]);
        }
        __syncthreads();                       // drains vmcnt before reads

        const int kc = r / 12;                 // conv tap 0..2
        const int hb = (r - kc * 12) * 32;     // h base within tap

        short8v afrag[4];
#pragma unroll
        for (int mt = 0; mt < 4; ++mt) {
            const int t = t0 + mt * 16 + ln + kc - 1;
            short8v a = (short8v){0, 0, 0, 0, 0, 0, 0, 0};
            if (t >= 0 && t < T_)
                a = *(const short8v*)(xbf + ((size_t)(b << 10) + t) * C_ + hb + (lq << 3));
            afrag[mt] = a;
        }
        short8v bfrag[6];
#pragma unroll
        for (int nt = 0; nt < 6; ++nt)
            bfrag[nt] = *(const short8v*)&slab[(nb + nt * 16 + ln) * 32 + (lq << 3)];

#pragma unroll
        for (int mt = 0; mt < 4; ++mt)
#pragma unroll
            for (int nt = 0; nt < 6; ++nt)
                acc[mt * 6 + nt] = __builtin_amdgcn_mfma_f32_16x16x32_bf16(
                    afrag[mt], bfrag[nt], acc[mt * 6 + nt], 0, 0, 0);
    }

    // ---- epilogue: bias+relu, LN over 384 cols/row (cross-wave via LDS) ----
    float bcol[6], gcol[6], becol[6], wcol[6];
#pragma unroll
    for (int nt = 0; nt < 6; ++nt) {
        const int col = nb + nt * 16 + ln;
        bcol[nt]  = bias[col];
        gcol[nt]  = gamma[col];
        becol[nt] = beta[col];
        wcol[nt]  = final_flag ? wo[col] : 0.f;
    }

#pragma unroll
    for (int mt = 0; mt < 4; ++mt) {
#pragma unroll
        for (int rg = 0; rg < 4; ++rg) {
            float s = 0.f, q = 0.f;
#pragma unroll
            for (int nt = 0; nt < 6; ++nt) {
                float v = acc[mt * 6 + nt][rg] + bcol[nt];
                v = v > 0.f ? v : 0.f;
                acc[mt * 6 + nt][rg] = v;
                s += v; q += v * v;
            }
#pragma unroll
            for (int off = 1; off < 16; off <<= 1) {
                s += __shfl_xor(s, off, 64);
                q += __shfl_xor(q, off, 64);
            }
            if (ln == mt * 4 + rg) {           // one writer lane per row
                rsum[wave][mt * 16 + lq * 4 + rg] = s;
                rsq [wave][mt * 16 + lq * 4 + rg] = q;
            }
        }
    }
    __syncthreads();

    float mean_[16], rstd_[16];
#pragma unroll
    for (int mt = 0; mt < 4; ++mt) {
#pragma unroll
        for (int rg = 0; rg < 4; ++rg) {
            const int row = mt * 16 + lq * 4 + rg;
            const float s = rsum[0][row] + rsum[1][row] + rsum[2][row] + rsum[3][row];
            const float q = rsq[0][row] + rsq[1][row] + rsq[2][row] + rsq[3][row];
            const float m = s * (1.f / 384.f);
            const float var = q * (1.f / 384.f) - m * m;
            mean_[mt * 4 + rg] = m;
            rstd_[mt * 4 + rg] = rsqrtf(var + 1e-5f);
        }
    }

    if (!final_flag) {
#pragma unroll
        for (int mt = 0; mt < 4; ++mt)
#pragma unroll
            for (int rg = 0; rg < 4; ++rg) {
                const float m = mean_[mt * 4 + rg], rs = rstd_[mt * 4 + rg];
                const int grow = R0 + mt * 16 + lq * 4 + rg;
#pragma unroll
                for (int nt = 0; nt < 6; ++nt) {
                    const float v = (acc[mt * 6 + nt][rg] - m) * rs * gcol[nt] + becol[nt];
                    hout[(size_t)grow * C_ + nb + nt * 16 + ln] = f2bf(v);
                }
            }
    } else {
        __syncthreads();                       // rsum about to be reused
#pragma unroll
        for (int mt = 0; mt < 4; ++mt) {
#pragma unroll
            for (int rg = 0; rg < 4; ++rg) {
                const float m = mean_[mt * 4 + rg], rs = rstd_[mt * 4 + rg];
                float p = 0.f;
#pragma unroll
                for (int nt = 0; nt < 6; ++nt)
                    p += ((acc[mt * 6 + nt][rg] - m) * rs * gcol[nt] + becol[nt]) * wcol[nt];
#pragma unroll
                for (int off = 1; off < 16; off <<= 1)
                    p += __shfl_xor(p, off, 64);
                if (ln == mt * 4 + rg)
                    rsum[wave][mt * 16 + lq * 4 + rg] = p;
            }
        }
        __syncthreads();
        if (tid < 64)
            pred[R0 + tid] = rsum[0][tid] + rsum[1][tid] + rsum[2][tid] + rsum[3][tid] + bo[0];
    }
}

// fp32 -> bf16 cast, 4 elems/thread
__global__ __launch_bounds__(256) void cast_x_kernel(
    const float* __restrict__ src, unsigned short* __restrict__ dst)
{
    const int i = blockIdx.x * 256 + threadIdx.x;   // over B*T*96
    const float4 v = *(const float4*)(src + (size_t)i * 4);
    ushort4 o;
    o.x = f2bf(v.x); o.y = f2bf(v.y); o.z = f2bf(v.z); o.w = f2bf(v.w);
    *(ushort4*)(dst + (size_t)i * 4) = o;
}

// w (1152,384) fp32 -> wpk (36,384,32) bf16: wpk[r][n][k] = w[r*32+k][n]
__global__ __launch_bounds__(256) void pack_w_kernel(
    const float* __restrict__ src, unsigned short* __restrict__ dst)
{
    const int o = blockIdx.x * 256 + threadIdx.x;   // 442368
    const int r = o >> 14;          // / 12288
    const int rem = o & 12287;
    const int n = rem >> 5;
    const int k = rem & 31;
    dst[o] = f2bf(src[(size_t)(r * 32 + k) * C_ + n]);
}

// xdst = xsrc + emb[searchsorted_left(bins, target)]; optional bf16 mirror
__global__ __launch_bounds__(256) void add_emb_kernel(
    const float* __restrict__ xsrc, const float* __restrict__ target,
    const float* __restrict__ bins, const float* __restrict__ emb,
    float* __restrict__ xdst, unsigned short* __restrict__ bfdst)
{
    const int g   = blockIdx.x * 256 + threadIdx.x;  // over B*T*96
    const int c4  = g % 96;
    const int row = g / 96;
    const float v = target[row];
    int lo = 0, hi = NBINS_;
    while (lo < hi) {
        const int mid = (lo + hi) >> 1;
        if (bins[mid] < v) lo = mid + 1; else hi = mid;
    }
    float4 xv = *(const float4*)(xsrc + (size_t)row * C_ + c4 * 4);
    const float4 ev = *(const float4*)(emb + (size_t)lo * C_ + c4 * 4);
    xv.x += ev.x; xv.y += ev.y; xv.z += ev.z; xv.w += ev.w;
    *(float4*)(xdst + (size_t)row * C_ + c4 * 4) = xv;
    if (bfdst) {
        ushort4 o;
        o.x = f2bf(xv.x); o.y = f2bf(xv.y); o.z = f2bf(xv.z); o.w = f2bf(xv.w);
        *(ushort4*)(bfdst + (size_t)row * C_ + c4 * 4) = o;
    }
}

// per-batch inclusive cumsum of duration (T=1024) + mel_len (as float)
__global__ __launch_bounds__(256) void cumsum_kernel(
    const int* __restrict__ dur, int* __restrict__ csum,
    float* __restrict__ mel_len)
{
    __shared__ int part[256];
    const int b = blockIdx.x;
    const int tid = threadIdx.x;
    int l[4];
    int s = 0;
#pragma unroll
    for (int i = 0; i < 4; ++i) { l[i] = dur[b * T_ + tid * 4 + i]; s += l[i]; }
    part[tid] = s;
    __syncthreads();
    for (int off = 1; off < 256; off <<= 1) {
        int u = 0;
        if (tid >= off) u = part[tid - off];
        __syncthreads();
        part[tid] += u;
        __syncthreads();
    }
    const int incl = part[tid];
    int run = incl - s;
#pragma unroll
    for (int i = 0; i < 4; ++i) {
        run += l[i];
        csum[b * T_ + tid * 4 + i] = run;
    }
    if (tid == 255) mel_len[b] = (float)incl;
}

__global__ __launch_bounds__(256) void length_reg_kernel(
    const float* __restrict__ x, const int* __restrict__ csum,
    float* __restrict__ out)
{
    const int g    = blockIdx.x * 256 + threadIdx.x;  // B*2048*96
    const int c4   = g % 96;
    const int rest = g / 96;
    const int frame = rest & (MAXLEN_ - 1);
    const int b     = rest >> 11;
    const int* cr = csum + b * T_;
    const int total = cr[T_ - 1];
    float4 v = make_float4(0.f, 0.f, 0.f, 0.f);
    if (frame < total) {
        int lo = 0, hi = T_;
        while (lo < hi) {
            const int mid = (lo + hi) >> 1;
            if (cr[mid] <= frame) lo = mid + 1; else hi = mid;
        }
        if (lo > T_ - 1) lo = T_ - 1;
        v = *(const float4*)(x + ((size_t)b * T_ + lo) * C_ + c4 * 4);
    }
    *(float4*)(out + (size_t)g * 4) = v;
}

extern "C" void kernel_launch(void* const* d_in, const int* in_sizes, int n_in,
                              void* d_out, int out_size, void* d_ws, size_t ws_size,
                              hipStream_t stream)
{
    const float* x        = (const float*)d_in[0];
    const int*   duration = (const int*)d_in[2];
    const float* P[3][10];
    for (int p = 0; p < 3; ++p)
        for (int q = 0; q < 10; ++q)
            P[p][q] = (const float*)d_in[4 + p * 10 + q];
    const float* pitch_bins    = (const float*)d_in[34];
    const float* energy_bins   = (const float*)d_in[35];
    const float* pitch_emb     = (const float*)d_in[36];
    const float* energy_emb    = (const float*)d_in[37];
    const float* pitch_target  = (const float*)d_in[38];
    const float* energy_target = (const float*)d_in[39];

    float* out_x      = (float*)d_out;                       // (B,2048,384)
    float* out_pitch  = out_x + (size_t)B_ * MAXLEN_ * C_;
    float* out_energy = out_pitch + B_ * T_;
    float* out_logdur = out_energy + B_ * T_;
    float* out_mellen = out_logdur + B_ * T_;

    // bf16 scratch lives in the x_out region (dead before length_reg writes it)
    unsigned short* h1b = (unsigned short*)out_x;            // 12.6M bf16
    unsigned short* xbf = h1b + (size_t)B_ * T_ * C_;
    unsigned short* x2b = xbf + (size_t)B_ * T_ * C_;
    unsigned short* wpk = x2b + (size_t)B_ * T_ * C_;        // 6 x 442368 bf16

    float* x2f  = (float*)d_ws;                              // (B,T,384) fp32
    int*   csum = (int*)(x2f + (size_t)B_ * T_ * C_);

    const dim3 blk(256);
    const size_t WPK1 = 442368;   // 36*384*32

    // prep: cast x, pack 6 weight tensors
    cast_x_kernel<<<12288, blk, 0, stream>>>(x, xbf);
    pack_w_kernel<<<1728, blk, 0, stream>>>(P[0][0], wpk + 0 * WPK1);
    pack_w_kernel<<<1728, blk, 0, stream>>>(P[0][4], wpk + 1 * WPK1);
    pack_w_kernel<<<1728, blk, 0, stream>>>(P[1][0], wpk + 2 * WPK1);
    pack_w_kernel<<<1728, blk, 0, stream>>>(P[1][4], wpk + 3 * WPK1);
    pack_w_kernel<<<1728, blk, 0, stream>>>(P[2][0], wpk + 4 * WPK1);
    pack_w_kernel<<<1728, blk, 0, stream>>>(P[2][4], wpk + 5 * WPK1);

    // duration predictor
    conv_mfma_kernel<<<512, blk, 0, stream>>>(xbf, wpk + 0 * WPK1,
        P[0][1], P[0][2], P[0][3], nullptr, nullptr, h1b, nullptr, 0);
    conv_mfma_kernel<<<512, blk, 0, stream>>>(h1b, wpk + 1 * WPK1,
        P[0][5], P[0][6], P[0][7], P[0][8], P[0][9], nullptr, out_logdur, 1);
    // pitch predictor
    conv_mfma_kernel<<<512, blk, 0, stream>>>(xbf, wpk + 2 * WPK1,
        P[1][1], P[1][2], P[1][3], nullptr, nullptr, h1b, nullptr, 0);
    conv_mfma_kernel<<<512, blk, 0, stream>>>(h1b, wpk + 3 * WPK1,
        P[1][5], P[1][6], P[1][7], P[1][8], P[1][9], nullptr, out_pitch, 1);
    // x2 = x + pitch_emb[...]
    add_emb_kernel<<<12288, blk, 0, stream>>>(x, pitch_target, pitch_bins,
                                              pitch_emb, x2f, x2b);
    // energy predictor (on x2)
    conv_mfma_kernel<<<512, blk, 0, stream>>>(x2b, wpk + 4 * WPK1,
        P[2][1], P[2][2], P[2][3], nullptr, nullptr, h1b, nullptr, 0);
    conv_mfma_kernel<<<512, blk, 0, stream>>>(h1b, wpk + 5 * WPK1,
        P[2][5], P[2][6], P[2][7], P[2][8], P[2][9], nullptr, out_energy, 1);
    // x2 += energy_emb[...] (fp32 only; no bf16 consumer afterwards)
    add_emb_kernel<<<12288, blk, 0, stream>>>(x2f, energy_target, energy_bins,
                                              energy_emb, x2f, nullptr);
    // cumsum + length regulate
    cumsum_kernel<<<B_, blk, 0, stream>>>(duration, csum, out_mellen);
    length_reg_kernel<<<24576, blk, 0, stream>>>(x2f, csum, out_x);
}

// Round 3
// 555.701 us; speedup vs baseline: 7.4393x; 1.2878x over previous
//
#include <hip/hip_runtime.h>

#define B_ 32
#define T_ 1024
#define C_ 384
#define MAXLEN_ 2048
#define NBINS_ 255

typedef __attribute__((ext_vector_type(8))) short short8v;   // 8 bf16 = 4 VGPRs
typedef __attribute__((ext_vector_type(4))) float floatx4;

__device__ __forceinline__ unsigned short f2bf(float f) {
    unsigned u = __float_as_uint(f);
    u += 0x7fffu + ((u >> 16) & 1u);   // RNE
    return (unsigned short)(u >> 16);
}

// ---------------------------------------------------------------------------
// Fused conv1d(K=3,SAME)+bias+relu+LayerNorm[+projection], bf16 MFMA.
// y[row,f] = sum_k A[row,k]*B[k,f], K=1152.
//  - A-tile (64 rows + 2 halo) in LDS, staged ONCE, padded row stride 392 bf16
//    (lane stride 196 dwords == 4 mod 32 -> conflict-free ds_read_b128).
//  - B read straight from global packed wpk[36][384][32] in fragment order
//    (L2-resident, all blocks share it), one-step register prefetch.
//  - NO barriers in the K-loop -> compiler schedules MFMA <-> vmem freely.
// Block: 256 thr = 4 waves; tile 64 rows x 384 cols; wave owns 96 cols.
// ---------------------------------------------------------------------------
#define ARS 392   // A row stride in bf16 (384 + 8 pad)

__global__ __launch_bounds__(256, 2) void conv_mfma_kernel(
    const unsigned short* __restrict__ xbf,   // (B*T,384) bf16
    const unsigned short* __restrict__ wpk,   // (36,384,32) bf16
    const float* __restrict__ bias,
    const float* __restrict__ gamma,
    const float* __restrict__ beta,
    const float* __restrict__ wo,             // (384) or null
    const float* __restrict__ bo,             // (1)   or null
    unsigned short* __restrict__ hout,        // bf16 (B*T,384) or null
    float* __restrict__ pred,                 // (B*T) or null
    int final_flag)
{
    __shared__ unsigned short As[66 * ARS];   // 51.7 KB
    __shared__ float rsum[4][64];
    __shared__ float rsq[4][64];

    const int tid  = threadIdx.x;
    const int wave = tid >> 6;
    const int lane = tid & 63;
    const int lq   = lane >> 4;     // quad 0..3
    const int ln   = lane & 15;
    const int bi   = blockIdx.x;    // 512 blocks
    const int R0   = bi << 6;       // global row base (b*1024 + t0)
    const int b    = bi >> 4;
    const int t0   = (bi & 15) << 6;
    const int nb   = wave * 96;     // wave's column base

    // ---- stage A-tile (rows t0-1 .. t0+64) into LDS, zero halo ----
    for (int i = tid; i < 66 * 48; i += 256) {
        const int row = i / 48;          // 0..65
        const int c   = i % 48;          // 16B chunk within row
        const int t   = t0 - 1 + row;
        short8v v = (short8v){0,0,0,0,0,0,0,0};
        if (t >= 0 && t < T_)
            v = *(const short8v*)(xbf + ((size_t)(b << 10) + t) * C_ + c * 8);
        *(short8v*)&As[row * ARS + c * 8] = v;
    }
    __syncthreads();

    floatx4 acc[24];
#pragma unroll
    for (int i = 0; i < 24; ++i) acc[i] = (floatx4){0.f, 0.f, 0.f, 0.f};

    // B fragment base for this lane: wpk[r][nb+ln][lq*8]
    const unsigned short* bbase = wpk + ((size_t)(nb + ln) << 5) + (lq << 3);

    short8v bnx[6];
#pragma unroll
    for (int nt = 0; nt < 6; ++nt)
        bnx[nt] = *(const short8v*)(bbase + (nt << 9));   // nt*16 cols * 32 k

    int kc = 0, hb = 0;
    for (int r = 0; r < 36; ++r) {
        short8v bcur[6];
#pragma unroll
        for (int nt = 0; nt < 6; ++nt) bcur[nt] = bnx[nt];
        if (r + 1 < 36) {
            const unsigned short* nb_ = bbase + (size_t)(r + 1) * 12288;
#pragma unroll
            for (int nt = 0; nt < 6; ++nt)
                bnx[nt] = *(const short8v*)(nb_ + (nt << 9));
        }

        // afrag: A[local_row = mt*16+ln+kc][hb + lq*8]
        short8v afrag[4];
#pragma unroll
        for (int mt = 0; mt < 4; ++mt)
            afrag[mt] = *(const short8v*)&As[(mt * 16 + ln + kc) * ARS + hb + (lq << 3)];

#pragma unroll
        for (int mt = 0; mt < 4; ++mt)
#pragma unroll
            for (int nt = 0; nt < 6; ++nt)
                acc[mt * 6 + nt] = __builtin_amdgcn_mfma_f32_16x16x32_bf16(
                    afrag[mt], bcur[nt], acc[mt * 6 + nt], 0, 0, 0);

        hb += 32;
        if (hb == 384) { hb = 0; ++kc; }
    }

    // ---- epilogue: bias+relu, LN over 384 cols/row (cross-wave via LDS) ----
    float bcol[6], gcol[6], becol[6], wcol[6];
#pragma unroll
    for (int nt = 0; nt < 6; ++nt) {
        const int col = nb + nt * 16 + ln;
        bcol[nt]  = bias[col];
        gcol[nt]  = gamma[col];
        becol[nt] = beta[col];
        wcol[nt]  = final_flag ? wo[col] : 0.f;
    }

#pragma unroll
    for (int mt = 0; mt < 4; ++mt) {
#pragma unroll
        for (int rg = 0; rg < 4; ++rg) {
            float s = 0.f, q = 0.f;
#pragma unroll
            for (int nt = 0; nt < 6; ++nt) {
                float v = acc[mt * 6 + nt][rg] + bcol[nt];
                v = v > 0.f ? v : 0.f;
                acc[mt * 6 + nt][rg] = v;
                s += v; q += v * v;
            }
#pragma unroll
            for (int off = 1; off < 16; off <<= 1) {
                s += __shfl_xor(s, off, 64);
                q += __shfl_xor(q, off, 64);
            }
            if (ln == mt * 4 + rg) {           // one writer lane per row
                rsum[wave][mt * 16 + lq * 4 + rg] = s;
                rsq [wave][mt * 16 + lq * 4 + rg] = q;
            }
        }
    }
    __syncthreads();

    float mean_[16], rstd_[16];
#pragma unroll
    for (int mt = 0; mt < 4; ++mt) {
#pragma unroll
        for (int rg = 0; rg < 4; ++rg) {
            const int row = mt * 16 + lq * 4 + rg;
            const float s = rsum[0][row] + rsum[1][row] + rsum[2][row] + rsum[3][row];
            const float q = rsq[0][row] + rsq[1][row] + rsq[2][row] + rsq[3][row];
            const float m = s * (1.f / 384.f);
            const float var = q * (1.f / 384.f) - m * m;
            mean_[mt * 4 + rg] = m;
            rstd_[mt * 4 + rg] = rsqrtf(var + 1e-5f);
        }
    }

    if (!final_flag) {
#pragma unroll
        for (int mt = 0; mt < 4; ++mt)
#pragma unroll
            for (int rg = 0; rg < 4; ++rg) {
                const float m = mean_[mt * 4 + rg], rs = rstd_[mt * 4 + rg];
                const int grow = R0 + mt * 16 + lq * 4 + rg;
#pragma unroll
                for (int nt = 0; nt < 6; ++nt) {
                    const float v = (acc[mt * 6 + nt][rg] - m) * rs * gcol[nt] + becol[nt];
                    hout[(size_t)grow * C_ + nb + nt * 16 + ln] = f2bf(v);
                }
            }
    } else {
        __syncthreads();                       // rsum about to be reused
#pragma unroll
        for (int mt = 0; mt < 4; ++mt) {
#pragma unroll
            for (int rg = 0; rg < 4; ++rg) {
                const float m = mean_[mt * 4 + rg], rs = rstd_[mt * 4 + rg];
                float p = 0.f;
#pragma unroll
                for (int nt = 0; nt < 6; ++nt)
                    p += ((acc[mt * 6 + nt][rg] - m) * rs * gcol[nt] + becol[nt]) * wcol[nt];
#pragma unroll
                for (int off = 1; off < 16; off <<= 1)
                    p += __shfl_xor(p, off, 64);
                if (ln == mt * 4 + rg)
                    rsum[wave][mt * 16 + lq * 4 + rg] = p;
            }
        }
        __syncthreads();
        if (tid < 64)
            pred[R0 + tid] = rsum[0][tid] + rsum[1][tid] + rsum[2][tid] + rsum[3][tid] + bo[0];
    }
}

// fp32 -> bf16 cast, 4 elems/thread
__global__ __launch_bounds__(256) void cast_x_kernel(
    const float* __restrict__ src, unsigned short* __restrict__ dst)
{
    const int i = blockIdx.x * 256 + threadIdx.x;   // over B*T*96
    const float4 v = *(const float4*)(src + (size_t)i * 4);
    ushort4 o;
    o.x = f2bf(v.x); o.y = f2bf(v.y); o.z = f2bf(v.z); o.w = f2bf(v.w);
    *(ushort4*)(dst + (size_t)i * 4) = o;
}

// w (1152,384) fp32 -> wpk (36,384,32) bf16: wpk[r][n][k] = w[r*32+k][n]
// one launch packs all 6 weight tensors (blockIdx.y selects)
__global__ __launch_bounds__(256) void pack_w_kernel(
    const float* __restrict__ s0, const float* __restrict__ s1,
    const float* __restrict__ s2, const float* __restrict__ s3,
    const float* __restrict__ s4, const float* __restrict__ s5,
    unsigned short* __restrict__ dst)
{
    const int wsel = blockIdx.y;
    const float* src = wsel == 0 ? s0 : wsel == 1 ? s1 : wsel == 2 ? s2
                     : wsel == 3 ? s3 : wsel == 4 ? s4 : s5;
    const int o = blockIdx.x * 256 + threadIdx.x;   // 442368
    const int r = o >> 14;          // / 12288
    const int rem = o & 12287;
    const int n = rem >> 5;
    const int k = rem & 31;
    dst[(size_t)wsel * 442368 + o] = f2bf(src[(size_t)(r * 32 + k) * C_ + n]);
}

// xdst = xsrc + emb[searchsorted_left(bins, target)]; optional bf16 mirror
__global__ __launch_bounds__(256) void add_emb_kernel(
    const float* __restrict__ xsrc, const float* __restrict__ target,
    const float* __restrict__ bins, const float* __restrict__ emb,
    float* __restrict__ xdst, unsigned short* __restrict__ bfdst)
{
    const int g   = blockIdx.x * 256 + threadIdx.x;  // over B*T*96
    const int c4  = g % 96;
    const int row = g / 96;
    const float v = target[row];
    int lo = 0, hi = NBINS_;
    while (lo < hi) {
        const int mid = (lo + hi) >> 1;
        if (bins[mid] < v) lo = mid + 1; else hi = mid;
    }
    float4 xv = *(const float4*)(xsrc + (size_t)row * C_ + c4 * 4);
    const float4 ev = *(const float4*)(emb + (size_t)lo * C_ + c4 * 4);
    xv.x += ev.x; xv.y += ev.y; xv.z += ev.z; xv.w += ev.w;
    *(float4*)(xdst + (size_t)row * C_ + c4 * 4) = xv;
    if (bfdst) {
        ushort4 o;
        o.x = f2bf(xv.x); o.y = f2bf(xv.y); o.z = f2bf(xv.z); o.w = f2bf(xv.w);
        *(ushort4*)(bfdst + (size_t)row * C_ + c4 * 4) = o;
    }
}

// per-batch inclusive cumsum of duration (T=1024) + mel_len (as float)
__global__ __launch_bounds__(256) void cumsum_kernel(
    const int* __restrict__ dur, int* __restrict__ csum,
    float* __restrict__ mel_len)
{
    __shared__ int part[256];
    const int b = blockIdx.x;
    const int tid = threadIdx.x;
    int l[4];
    int s = 0;
#pragma unroll
    for (int i = 0; i < 4; ++i) { l[i] = dur[b * T_ + tid * 4 + i]; s += l[i]; }
    part[tid] = s;
    __syncthreads();
    for (int off = 1; off < 256; off <<= 1) {
        int u = 0;
        if (tid >= off) u = part[tid - off];
        __syncthreads();
        part[tid] += u;
        __syncthreads();
    }
    const int incl = part[tid];
    int run = incl - s;
#pragma unroll
    for (int i = 0; i < 4; ++i) {
        run += l[i];
        csum[b * T_ + tid * 4 + i] = run;
    }
    if (tid == 255) mel_len[b] = (float)incl;
}

__global__ __launch_bounds__(256) void length_reg_kernel(
    const float* __restrict__ x, const int* __restrict__ csum,
    float* __restrict__ out)
{
    const int g    = blockIdx.x * 256 + threadIdx.x;  // B*2048*96
    const int c4   = g % 96;
    const int rest = g / 96;
    const int frame = rest & (MAXLEN_ - 1);
    const int b     = rest >> 11;
    const int* cr = csum + b * T_;
    const int total = cr[T_ - 1];
    float4 v = make_float4(0.f, 0.f, 0.f, 0.f);
    if (frame < total) {
        int lo = 0, hi = T_;
        while (lo < hi) {
            const int mid = (lo + hi) >> 1;
            if (cr[mid] <= frame) lo = mid + 1; else hi = mid;
        }
        if (lo > T_ - 1) lo = T_ - 1;
        v = *(const float4*)(x + ((size_t)b * T_ + lo) * C_ + c4 * 4);
    }
    *(float4*)(out + (size_t)g * 4) = v;
}

extern "C" void kernel_launch(void* const* d_in, const int* in_sizes, int n_in,
                              void* d_out, int out_size, void* d_ws, size_t ws_size,
                              hipStream_t stream)
{
    const float* x        = (const float*)d_in[0];
    const int*   duration = (const int*)d_in[2];
    const float* P[3][10];
    for (int p = 0; p < 3; ++p)
        for (int q = 0; q < 10; ++q)
            P[p][q] = (const float*)d_in[4 + p * 10 + q];
    const float* pitch_bins    = (const float*)d_in[34];
    const float* energy_bins   = (const float*)d_in[35];
    const float* pitch_emb     = (const float*)d_in[36];
    const float* energy_emb    = (const float*)d_in[37];
    const float* pitch_target  = (const float*)d_in[38];
    const float* energy_target = (const float*)d_in[39];

    float* out_x      = (float*)d_out;                       // (B,2048,384)
    float* out_pitch  = out_x + (size_t)B_ * MAXLEN_ * C_;
    float* out_energy = out_pitch + B_ * T_;
    float* out_logdur = out_energy + B_ * T_;
    float* out_mellen = out_logdur + B_ * T_;

    // bf16 scratch lives in the x_out region (dead before length_reg writes it)
    unsigned short* h1b = (unsigned short*)out_x;            // 12.6M bf16
    unsigned short* xbf = h1b + (size_t)B_ * T_ * C_;
    unsigned short* x2b = xbf + (size_t)B_ * T_ * C_;
    unsigned short* wpk = x2b + (size_t)B_ * T_ * C_;        // 6 x 442368 bf16

    float* x2f  = (float*)d_ws;                              // (B,T,384) fp32
    int*   csum = (int*)(x2f + (size_t)B_ * T_ * C_);

    const dim3 blk(256);
    const size_t WPK1 = 442368;   // 36*384*32

    // prep: cast x, pack all 6 weight tensors in one launch
    cast_x_kernel<<<12288, blk, 0, stream>>>(x, xbf);
    pack_w_kernel<<<dim3(1728, 6), blk, 0, stream>>>(
        P[0][0], P[0][4], P[1][0], P[1][4], P[2][0], P[2][4], wpk);

    // duration predictor
    conv_mfma_kernel<<<512, blk, 0, stream>>>(xbf, wpk + 0 * WPK1,
        P[0][1], P[0][2], P[0][3], nullptr, nullptr, h1b, nullptr, 0);
    conv_mfma_kernel<<<512, blk, 0, stream>>>(h1b, wpk + 1 * WPK1,
        P[0][5], P[0][6], P[0][7], P[0][8], P[0][9], nullptr, out_logdur, 1);
    // pitch predictor
    conv_mfma_kernel<<<512, blk, 0, stream>>>(xbf, wpk + 2 * WPK1,
        P[1][1], P[1][2], P[1][3], nullptr, nullptr, h1b, nullptr, 0);
    conv_mfma_kernel<<<512, blk, 0, stream>>>(h1b, wpk + 3 * WPK1,
        P[1][5], P[1][6], P[1][7], P[1][8], P[1][9], nullptr, out_pitch, 1);
    // x2 = x + pitch_emb[...]
    add_emb_kernel<<<12288, blk, 0, stream>>>(x, pitch_target, pitch_bins,
                                              pitch_emb, x2f, x2b);
    // energy predictor (on x2)
    conv_mfma_kernel<<<512, blk, 0, stream>>>(x2b, wpk + 4 * WPK1,
        P[2][1], P[2][2], P[2][3], nullptr, nullptr, h1b, nullptr, 0);
    conv_mfma_kernel<<<512, blk, 0, stream>>>(h1b, wpk + 5 * WPK1,
        P[2][5], P[2][6], P[2][7], P[2][8], P[2][9], nullptr, out_energy, 1);
    // x2 += energy_emb[...] (fp32 only; no bf16 consumer afterwards)
    add_emb_kernel<<<12288, blk, 0, stream>>>(x2f, energy_target, energy_bins,
                                              energy_emb, x2f, nullptr);
    // cumsum + length regulate
    cumsum_kernel<<<B_, blk, 0, stream>>>(duration, csum, out_mellen);
    length_reg_kernel<<<24576, blk, 0, stream>>>(x2f, csum, out_x);
}

// Round 4
// 543.874 us; speedup vs baseline: 7.6011x; 1.0217x over previous
//
#include <hip/hip_runtime.h>

#define B_ 32
#define T_ 1024
#define C_ 384
#define MAXLEN_ 2048
#define NBINS_ 255
#define WPK1 442368          /* 36*384*32 packed bf16 elems per weight */
#define BTC  (32 * 1024 * 384)

typedef __attribute__((ext_vector_type(8))) short short8v;   // 8 bf16 = 4 VGPRs
typedef __attribute__((ext_vector_type(4))) float floatx4;

__device__ __forceinline__ unsigned short f2bf(float f) {
    unsigned u = __float_as_uint(f);
    u += 0x7fffu + ((u >> 16) & 1u);   // RNE
    return (unsigned short)(u >> 16);
}
__device__ __forceinline__ float bf2f(unsigned short h) {
    return __uint_as_float(((unsigned)h) << 16);
}

struct CvP {
    const unsigned short* xin;    // + p*xin_stride
    size_t xin_stride;
    const unsigned short* wpk;    // + p*WPK1
    const float* bias[3];
    const float* gamma[3];
    const float* beta[3];
    const float* wo[3];
    const float* bo[3];
    unsigned short* hout;         // + p*BTC (layer1) or null
    float* pred[3];               // layer2
    const float* pbins;           // pitch-emb fusion (layer1, p==2)
    const float* pemb;
    const float* ptgt;
    int final_flag;
};

// ---------------------------------------------------------------------------
// 3-predictor fused conv1d(K=3,SAME)+bias+relu+LN[+projection], bf16 MFMA.
// Block: 512 thr = 8 waves = 2 row-groups x 4 col-groups; tile 128 rows x 384.
// A-tile (128+2 halo rows, pad stride 392) staged once in LDS; B read from
// global packed wpk in fragment order with DISTANCE-2 register prefetch.
// Both row-groups read identical B addresses -> L1 dedup halves L2 traffic.
// ---------------------------------------------------------------------------
#define ARS 392   // A row stride in bf16 (384 + 8 pad)

__global__ __launch_bounds__(512, 2) void conv_mfma3(CvP P)
{
    __shared__ unsigned short As[130 * ARS];   // 101.9 KB
    __shared__ float rsum[8][64];
    __shared__ float rsq[8][64];

    const int tid  = threadIdx.x;
    const int wave = tid >> 6;
    const int wg   = wave >> 2;      // row half 0/1
    const int wv   = wave & 3;       // col group
    const int lane = tid & 63;
    const int lq   = lane >> 4;
    const int ln   = lane & 15;
    const int p    = blockIdx.x >> 8;       // predictor 0..2
    const int bi   = blockIdx.x & 255;      // tile 0..255
    const int b    = bi >> 3;
    const int t0   = (bi & 7) << 7;         // 128-row tiles
    const int nb   = wv * 96;

    const unsigned short* xin = P.xin + (size_t)p * P.xin_stride;
    const bool fuse_emb = (!P.final_flag) && (p == 2);

    // ---- stage A-tile rows t0-1 .. t0+128 (zero halo), optional emb add ----
    for (int i = tid; i < 130 * 48; i += 512) {
        const int row = i / 48;
        const int c   = i - row * 48;
        const int t   = t0 - 1 + row;
        short8v v = (short8v){0,0,0,0,0,0,0,0};
        if ((unsigned)t < (unsigned)T_) {
            v = *(const short8v*)(xin + ((size_t)(b << 10) + t) * C_ + c * 8);
            if (fuse_emb) {
                const float tg = P.ptgt[(b << 10) + t];
                int lo = 0, hi = NBINS_;
                while (lo < hi) {
                    const int mid = (lo + hi) >> 1;
                    if (P.pbins[mid] < tg) lo = mid + 1; else hi = mid;
                }
                const float* er = P.pemb + (size_t)lo * C_ + c * 8;
#pragma unroll
                for (int j = 0; j < 8; ++j) {
                    const float f = bf2f((unsigned short)v[j]) + er[j];
                    v[j] = (short)f2bf(f);
                }
            }
        }
        *(short8v*)&As[row * ARS + c * 8] = v;
    }
    __syncthreads();

    floatx4 acc[24];
#pragma unroll
    for (int i = 0; i < 24; ++i) acc[i] = (floatx4){0.f, 0.f, 0.f, 0.f};

    const unsigned short* bbase =
        P.wpk + (size_t)p * WPK1 + ((size_t)(nb + ln) << 5) + (lq << 3);

    short8v bA[6], bB[6];
#pragma unroll
    for (int nt = 0; nt < 6; ++nt) {
        bA[nt] = *(const short8v*)(bbase + (nt << 9));
        bB[nt] = *(const short8v*)(bbase + 12288 + (nt << 9));
    }

    int kc = 0, hb = 0;
    for (int r = 0; r < 36; r += 2) {
        // -------- even: consume bA (step r) --------
        {
            short8v afrag[4];
#pragma unroll
            for (int mt = 0; mt < 4; ++mt)
                afrag[mt] = *(const short8v*)
                    &As[(wg * 64 + mt * 16 + ln + kc) * ARS + hb + (lq << 3)];
#pragma unroll
            for (int mt = 0; mt < 4; ++mt)
#pragma unroll
                for (int nt = 0; nt < 6; ++nt)
                    acc[mt * 6 + nt] = __builtin_amdgcn_mfma_f32_16x16x32_bf16(
                        afrag[mt], bA[nt], acc[mt * 6 + nt], 0, 0, 0);
            if (r + 2 < 36) {
                const unsigned short* np_ = bbase + (size_t)(r + 2) * 12288;
#pragma unroll
                for (int nt = 0; nt < 6; ++nt)
                    bA[nt] = *(const short8v*)(np_ + (nt << 9));
            }
            hb += 32; if (hb == 384) { hb = 0; ++kc; }
        }
        // -------- odd: consume bB (step r+1) --------
        {
            short8v afrag[4];
#pragma unroll
            for (int mt = 0; mt < 4; ++mt)
                afrag[mt] = *(const short8v*)
                    &As[(wg * 64 + mt * 16 + ln + kc) * ARS + hb + (lq << 3)];
#pragma unroll
            for (int mt = 0; mt < 4; ++mt)
#pragma unroll
                for (int nt = 0; nt < 6; ++nt)
                    acc[mt * 6 + nt] = __builtin_amdgcn_mfma_f32_16x16x32_bf16(
                        afrag[mt], bB[nt], acc[mt * 6 + nt], 0, 0, 0);
            if (r + 3 < 36) {
                const unsigned short* np_ = bbase + (size_t)(r + 3) * 12288;
#pragma unroll
                for (int nt = 0; nt < 6; ++nt)
                    bB[nt] = *(const short8v*)(np_ + (nt << 9));
            }
            hb += 32; if (hb == 384) { hb = 0; ++kc; }
        }
    }

    // ---- epilogue: bias+relu, LN over 384 cols/row ----
    float bcol[6], gcol[6], becol[6], wcol[6];
#pragma unroll
    for (int nt = 0; nt < 6; ++nt) {
        const int col = nb + nt * 16 + ln;
        bcol[nt]  = P.bias[p][col];
        gcol[nt]  = P.gamma[p][col];
        becol[nt] = P.beta[p][col];
        wcol[nt]  = P.final_flag ? P.wo[p][col] : 0.f;
    }

#pragma unroll
    for (int mt = 0; mt < 4; ++mt) {
#pragma unroll
        for (int rg = 0; rg < 4; ++rg) {
            float s = 0.f, q = 0.f;
#pragma unroll
            for (int nt = 0; nt < 6; ++nt) {
                float v = acc[mt * 6 + nt][rg] + bcol[nt];
                v = v > 0.f ? v : 0.f;
                acc[mt * 6 + nt][rg] = v;
                s += v; q += v * v;
            }
#pragma unroll
            for (int off = 1; off < 16; off <<= 1) {
                s += __shfl_xor(s, off, 64);
                q += __shfl_xor(q, off, 64);
            }
            if (ln == mt * 4 + rg) {
                rsum[wave][mt * 16 + lq * 4 + rg] = s;
                rsq [wave][mt * 16 + lq * 4 + rg] = q;
            }
        }
    }
    __syncthreads();

    float mean_[16], rstd_[16];
#pragma unroll
    for (int mt = 0; mt < 4; ++mt) {
#pragma unroll
        for (int rg = 0; rg < 4; ++rg) {
            const int row = mt * 16 + lq * 4 + rg;
            const int wb  = wg << 2;
            const float s = rsum[wb][row] + rsum[wb+1][row] + rsum[wb+2][row] + rsum[wb+3][row];
            const float q = rsq[wb][row] + rsq[wb+1][row] + rsq[wb+2][row] + rsq[wb+3][row];
            const float m = s * (1.f / 384.f);
            const float var = q * (1.f / 384.f) - m * m;
            mean_[mt * 4 + rg] = m;
            rstd_[mt * 4 + rg] = rsqrtf(var + 1e-5f);
        }
    }

    if (!P.final_flag) {
        unsigned short* hout = P.hout + (size_t)p * BTC;
#pragma unroll
        for (int mt = 0; mt < 4; ++mt)
#pragma unroll
            for (int rg = 0; rg < 4; ++rg) {
                const float m = mean_[mt * 4 + rg], rs = rstd_[mt * 4 + rg];
                const int grow = (bi << 7) + wg * 64 + mt * 16 + lq * 4 + rg;
#pragma unroll
                for (int nt = 0; nt < 6; ++nt) {
                    const float v = (acc[mt * 6 + nt][rg] - m) * rs * gcol[nt] + becol[nt];
                    hout[((size_t)b << 10) * 0 + (size_t)grow * C_ + nb + nt * 16 + ln] = f2bf(v);
                }
            }
    } else {
        __syncthreads();                       // rsum about to be reused
#pragma unroll
        for (int mt = 0; mt < 4; ++mt) {
#pragma unroll
            for (int rg = 0; rg < 4; ++rg) {
                const float m = mean_[mt * 4 + rg], rs = rstd_[mt * 4 + rg];
                float pr = 0.f;
#pragma unroll
                for (int nt = 0; nt < 6; ++nt)
                    pr += ((acc[mt * 6 + nt][rg] - m) * rs * gcol[nt] + becol[nt]) * wcol[nt];
#pragma unroll
                for (int off = 1; off < 16; off <<= 1)
                    pr += __shfl_xor(pr, off, 64);
                if (ln == mt * 4 + rg)
                    rsum[wave][mt * 16 + lq * 4 + rg] = pr;
            }
        }
        __syncthreads();
        if (tid < 128) {
            const int half = tid >> 6, r_ = tid & 63, wb = half << 2;
            P.pred[p][(bi << 7) + tid] =
                rsum[wb][r_] + rsum[wb+1][r_] + rsum[wb+2][r_] + rsum[wb+3][r_] + P.bo[p][0];
        }
    }
}

// fp32 -> bf16 cast, 4 elems/thread
__global__ __launch_bounds__(256) void cast_x_kernel(
    const float* __restrict__ src, unsigned short* __restrict__ dst)
{
    const int i = blockIdx.x * 256 + threadIdx.x;   // over B*T*96
    const float4 v = *(const float4*)(src + (size_t)i * 4);
    ushort4 o;
    o.x = f2bf(v.x); o.y = f2bf(v.y); o.z = f2bf(v.z); o.w = f2bf(v.w);
    *(ushort4*)(dst + (size_t)i * 4) = o;
}

// w (1152,384) fp32 -> wpk (36,384,32) bf16, all 6 tensors (blockIdx.y)
__global__ __launch_bounds__(256) void pack_w_kernel(
    const float* __restrict__ s0, const float* __restrict__ s1,
    const float* __restrict__ s2, const float* __restrict__ s3,
    const float* __restrict__ s4, const float* __restrict__ s5,
    unsigned short* __restrict__ dst)
{
    const int wsel = blockIdx.y;
    const float* src = wsel == 0 ? s0 : wsel == 1 ? s1 : wsel == 2 ? s2
                     : wsel == 3 ? s3 : wsel == 4 ? s4 : s5;
    const int o = blockIdx.x * 256 + threadIdx.x;   // 442368
    const int r = o >> 14;
    const int rem = o & 12287;
    const int n = rem >> 5;
    const int k = rem & 31;
    dst[(size_t)wsel * WPK1 + o] = f2bf(src[(size_t)(r * 32 + k) * C_ + n]);
}

// per-batch inclusive cumsum of duration (T=1024) + mel_len
__global__ __launch_bounds__(256) void cumsum_kernel(
    const int* __restrict__ dur, int* __restrict__ csum,
    float* __restrict__ mel_len)
{
    __shared__ int part[256];
    const int b = blockIdx.x;
    const int tid = threadIdx.x;
    int l[4];
    int s = 0;
#pragma unroll
    for (int i = 0; i < 4; ++i) { l[i] = dur[b * T_ + tid * 4 + i]; s += l[i]; }
    part[tid] = s;
    __syncthreads();
    for (int off = 1; off < 256; off <<= 1) {
        int u = 0;
        if (tid >= off) u = part[tid - off];
        __syncthreads();
        part[tid] += u;
        __syncthreads();
    }
    const int incl = part[tid];
    int run = incl - s;
#pragma unroll
    for (int i = 0; i < 4; ++i) {
        run += l[i];
        csum[b * T_ + tid * 4 + i] = run;
    }
    if (tid == 255) mel_len[b] = (float)incl;
}

// out[b,frame,:] = valid ? x[b,t,:] + pemb[pi(b,t)] + eemb[ei(b,t)] : 0  (fp32 exact)
__global__ __launch_bounds__(256) void length_reg_kernel(
    const float* __restrict__ x, const int* __restrict__ csum,
    const float* __restrict__ pbins, const float* __restrict__ pemb,
    const float* __restrict__ ptgt,
    const float* __restrict__ ebins, const float* __restrict__ eemb,
    const float* __restrict__ etgt,
    float* __restrict__ out)
{
    const int g    = blockIdx.x * 256 + threadIdx.x;  // B*2048*96
    const int c4   = g % 96;
    const int rest = g / 96;
    const int frame = rest & (MAXLEN_ - 1);
    const int b     = rest >> 11;
    const int* cr = csum + (b << 10);
    const int total = cr[T_ - 1];
    float4 v = make_float4(0.f, 0.f, 0.f, 0.f);
    if (frame < total) {
        int lo = 0, hi = T_;
        while (lo < hi) {
            const int mid = (lo + hi) >> 1;
            if (cr[mid] <= frame) lo = mid + 1; else hi = mid;
        }
        const int t = lo > T_ - 1 ? T_ - 1 : lo;
        const int row = (b << 10) + t;
        v = *(const float4*)(x + (size_t)row * C_ + c4 * 4);
        const float ptg = ptgt[row];
        int plo = 0, phi = NBINS_;
        while (plo < phi) {
            const int mid = (plo + phi) >> 1;
            if (pbins[mid] < ptg) plo = mid + 1; else phi = mid;
        }
        const float etg = etgt[row];
        int elo = 0, ehi = NBINS_;
        while (elo < ehi) {
            const int mid = (elo + ehi) >> 1;
            if (ebins[mid] < etg) elo = mid + 1; else ehi = mid;
        }
        const float4 pe = *(const float4*)(pemb + (size_t)plo * C_ + c4 * 4);
        const float4 ee = *(const float4*)(eemb + (size_t)elo * C_ + c4 * 4);
        v.x += pe.x + ee.x; v.y += pe.y + ee.y;
        v.z += pe.z + ee.z; v.w += pe.w + ee.w;
    }
    *(float4*)(out + (size_t)g * 4) = v;
}

extern "C" void kernel_launch(void* const* d_in, const int* in_sizes, int n_in,
                              void* d_out, int out_size, void* d_ws, size_t ws_size,
                              hipStream_t stream)
{
    const float* x        = (const float*)d_in[0];
    const int*   duration = (const int*)d_in[2];
    const float* P[3][10];
    for (int p = 0; p < 3; ++p)
        for (int q = 0; q < 10; ++q)
            P[p][q] = (const float*)d_in[4 + p * 10 + q];
    const float* pitch_bins    = (const float*)d_in[34];
    const float* energy_bins   = (const float*)d_in[35];
    const float* pitch_emb     = (const float*)d_in[36];
    const float* energy_emb    = (const float*)d_in[37];
    const float* pitch_target  = (const float*)d_in[38];
    const float* energy_target = (const float*)d_in[39];

    float* out_x      = (float*)d_out;                       // (B,2048,384)
    float* out_pitch  = out_x + (size_t)B_ * MAXLEN_ * C_;
    float* out_energy = out_pitch + B_ * T_;
    float* out_logdur = out_energy + B_ * T_;
    float* out_mellen = out_logdur + B_ * T_;

    // scratch in the x_out region (dead before length_reg writes it):
    // [xbf | h1b(p=0) | h1b(p=1) | h1b(p=2)] = exactly B*2048*384*4 bytes
    unsigned short* xbf = (unsigned short*)out_x;
    unsigned short* h1b = xbf + (size_t)BTC;

    unsigned short* wpk = (unsigned short*)d_ws;             // 6*WPK1 bf16
    int* csum = (int*)(wpk + (size_t)6 * WPK1);

    const dim3 blk(256);

    cast_x_kernel<<<12288, blk, 0, stream>>>(x, xbf);
    pack_w_kernel<<<dim3(1728, 6), blk, 0, stream>>>(
        P[0][0], P[0][4], P[1][0], P[1][4], P[2][0], P[2][4], wpk);

    CvP P1;
    P1.xin = xbf; P1.xin_stride = 0; P1.wpk = wpk;
    for (int p = 0; p < 3; ++p) {
        P1.bias[p]  = P[p][1];
        P1.gamma[p] = P[p][2];
        P1.beta[p]  = P[p][3];
        P1.wo[p]    = nullptr;
        P1.bo[p]    = nullptr;
        P1.pred[p]  = nullptr;
    }
    P1.hout = h1b;
    P1.pbins = pitch_bins; P1.pemb = pitch_emb; P1.ptgt = pitch_target;
    P1.final_flag = 0;

    CvP P2;
    P2.xin = h1b; P2.xin_stride = BTC; P2.wpk = wpk + (size_t)3 * WPK1;
    for (int p = 0; p < 3; ++p) {
        P2.bias[p]  = P[p][5];
        P2.gamma[p] = P[p][6];
        P2.beta[p]  = P[p][7];
        P2.wo[p]    = P[p][8];
        P2.bo[p]    = P[p][9];
    }
    P2.pred[0] = out_logdur; P2.pred[1] = out_pitch; P2.pred[2] = out_energy;
    P2.hout = nullptr;
    P2.pbins = nullptr; P2.pemb = nullptr; P2.ptgt = nullptr;
    P2.final_flag = 1;

    conv_mfma3<<<768, dim3(512), 0, stream>>>(P1);
    conv_mfma3<<<768, dim3(512), 0, stream>>>(P2);

    cumsum_kernel<<<B_, blk, 0, stream>>>(duration, csum, out_mellen);
    length_reg_kernel<<<24576, blk, 0, stream>>>(
        x, csum, pitch_bins, pitch_emb, pitch_target,
        energy_bins, energy_emb, energy_target, out_x);
}

// Round 5
// 502.047 us; speedup vs baseline: 8.2343x; 1.0833x over previous
//
#include <hip/hip_runtime.h>

#define B_ 32
#define T_ 1024
#define C_ 384
#define MAXLEN_ 2048
#define NBINS_ 255
#define WPK1 442368          /* 36*4*6*512 packed bf16 elems per weight */
#define BTC  (32 * 1024 * 384)
#define ARS 392              /* A-tile row stride in bf16 */

typedef __attribute__((ext_vector_type(8))) short short8v;   // 8 bf16 = 4 VGPRs
typedef __attribute__((ext_vector_type(4))) float floatx4;

__device__ __forceinline__ unsigned short f2bf(float f) {
    unsigned u = __float_as_uint(f);
    u += 0x7fffu + ((u >> 16) & 1u);   // RNE
    return (unsigned short)(u >> 16);
}

struct CvP {
    const float* xf;              // layer1 input (fp32 x)
    const unsigned short* xb;     // layer2 input base (h1b), + p*BTC
    const unsigned short* wpk;    // + p*WPK1
    const float* bias[3];
    const float* gamma[3];
    const float* beta[3];
    const float* wo[3];
    const float* bo[3];
    unsigned short* hout;         // layer1 out, + p*BTC
    float* pred[3];               // layer2 out
    const float* pbins;           // pitch-emb fusion (layer1, p==2)
    const float* pemb;
    const float* ptgt;
    int final_flag;
};

// ---------------------------------------------------------------------------
// 3-predictor fused conv1d(K=3,SAME)+bias+relu+LN[+projection], bf16 MFMA.
// Block: 256 thr = 4 waves, tile 64 rows x 384 cols; wave owns 96 cols.
// A-tile (64+2 halo rows, stride 392) staged once in LDS (layer1: cast from
// fp32 + optional pitch-emb add). B packed FRAGMENT-MAJOR: wpk[r][wv][nt] is
// one contiguous 1 KB wave-load (lane*16B) -> perfectly coalesced, nt offsets
// immediate. Distance-2 register prefetch, K-loop fully unrolled (LDS offsets
// all 16-bit immediates). rsum/rsq alias the A-tile -> LDS 51.75 KB ->
// 3 blocks/CU; consecutive blocks share p -> L1 dedups B across blocks.
// ---------------------------------------------------------------------------
__global__ __launch_bounds__(256, 2) void conv_mfma3(CvP P)
{
    __shared__ unsigned short As[66 * ARS];   // 51.75 KB
    float* rsum = (float*)As;                 // [4][64] aliased (post-K-loop)
    float* rsq  = rsum + 256;

    const int tid  = threadIdx.x;
    const int wave = tid >> 6;      // col group 0..3
    const int lane = tid & 63;
    const int lq   = lane >> 4;
    const int ln   = lane & 15;
    const int p    = blockIdx.x >> 9;       // predictor 0..2
    const int bi   = blockIdx.x & 511;      // tile 0..511
    const int b    = bi >> 4;
    const int t0   = (bi & 15) << 6;        // 64-row tiles
    const int nb   = wave * 96;

    // ---- B prefetch, steps 0 and 1 (issued before staging to hide latency)
    const unsigned short* bbase =
        P.wpk + (size_t)p * WPK1 + wave * 3072 + (size_t)lane * 8;
    short8v bA[6], bB[6];
#pragma unroll
    for (int nt = 0; nt < 6; ++nt) {
        bA[nt] = *(const short8v*)(bbase + (nt << 9));
        bB[nt] = *(const short8v*)(bbase + 12288 + (nt << 9));
    }

    // ---- stage A-tile rows t0-1 .. t0+64 (zero halo) ----
    if (!P.final_flag) {
        // layer1: cast fp32 x -> bf16; p==2 additionally adds pitch emb
        const bool fuse_emb = (p == 2);
        for (int i = tid; i < 66 * 48; i += 256) {
            const int row = i / 48;
            const int c   = i - row * 48;
            const int t   = t0 - 1 + row;
            short8v v = (short8v){0,0,0,0,0,0,0,0};
            if ((unsigned)t < (unsigned)T_) {
                const float* sp = P.xf + ((size_t)(b << 10) + t) * C_ + c * 8;
                float f[8];
                *(float4*)&f[0] = *(const float4*)sp;
                *(float4*)&f[4] = *(const float4*)(sp + 4);
                if (fuse_emb) {
                    const float tg = P.ptgt[(b << 10) + t];
                    int lo = 0, hi = NBINS_;
                    while (lo < hi) {
                        const int mid = (lo + hi) >> 1;
                        if (P.pbins[mid] < tg) lo = mid + 1; else hi = mid;
                    }
                    const float* er = P.pemb + (size_t)lo * C_ + c * 8;
#pragma unroll
                    for (int j = 0; j < 8; ++j) f[j] += er[j];
                }
#pragma unroll
                for (int j = 0; j < 8; ++j) v[j] = (short)f2bf(f[j]);
            }
            *(short8v*)&As[row * ARS + c * 8] = v;
        }
    } else {
        const unsigned short* xb = P.xb + (size_t)p * BTC;
        for (int i = tid; i < 66 * 48; i += 256) {
            const int row = i / 48;
            const int c   = i - row * 48;
            const int t   = t0 - 1 + row;
            short8v v = (short8v){0,0,0,0,0,0,0,0};
            if ((unsigned)t < (unsigned)T_)
                v = *(const short8v*)(xb + ((size_t)(b << 10) + t) * C_ + c * 8);
            *(short8v*)&As[row * ARS + c * 8] = v;
        }
    }
    __syncthreads();

    floatx4 acc[24];
#pragma unroll
    for (int i = 0; i < 24; ++i) acc[i] = (floatx4){0.f, 0.f, 0.f, 0.f};

    // single LDS vaddr; everything else is a 16-bit immediate
    const unsigned short* abase = &As[ln * ARS + lq * 8];
    const unsigned short* bpA = bbase + 2 * 12288;
    const unsigned short* bpB = bbase + 3 * 12288;

#pragma unroll
    for (int kc = 0; kc < 3; ++kc) {
#pragma unroll
        for (int h2 = 0; h2 < 6; ++h2) {
            const int hb = h2 * 64;
            const int r  = kc * 12 + h2 * 2;
            // -------- even step: consume bA --------
            {
                short8v afrag[4];
#pragma unroll
                for (int mt = 0; mt < 4; ++mt)
                    afrag[mt] = *(const short8v*)(abase + (mt * 16 + kc) * ARS + hb);
#pragma unroll
                for (int mt = 0; mt < 4; ++mt)
#pragma unroll
                    for (int nt = 0; nt < 6; ++nt)
                        acc[mt * 6 + nt] = __builtin_amdgcn_mfma_f32_16x16x32_bf16(
                            afrag[mt], bA[nt], acc[mt * 6 + nt], 0, 0, 0);
                if (r + 2 < 36) {
#pragma unroll
                    for (int nt = 0; nt < 6; ++nt)
                        bA[nt] = *(const short8v*)(bpA + (nt << 9));
                    bpA += 24576;
                }
            }
            // -------- odd step: consume bB --------
            {
                short8v afrag[4];
#pragma unroll
                for (int mt = 0; mt < 4; ++mt)
                    afrag[mt] = *(const short8v*)(abase + (mt * 16 + kc) * ARS + hb + 32);
#pragma unroll
                for (int mt = 0; mt < 4; ++mt)
#pragma unroll
                    for (int nt = 0; nt < 6; ++nt)
                        acc[mt * 6 + nt] = __builtin_amdgcn_mfma_f32_16x16x32_bf16(
                            afrag[mt], bB[nt], acc[mt * 6 + nt], 0, 0, 0);
                if (r + 3 < 36) {
#pragma unroll
                    for (int nt = 0; nt < 6; ++nt)
                        bB[nt] = *(const short8v*)(bpB + (nt << 9));
                    bpB += 24576;
                }
            }
        }
    }
    __syncthreads();   // all As reads done before aliasing it as rsum/rsq

    // ---- epilogue: bias+relu, LN over 384 cols/row ----
    float bcol[6], gcol[6], becol[6], wcol[6];
#pragma unroll
    for (int nt = 0; nt < 6; ++nt) {
        const int col = nb + nt * 16 + ln;
        bcol[nt]  = P.bias[p][col];
        gcol[nt]  = P.gamma[p][col];
        becol[nt] = P.beta[p][col];
        wcol[nt]  = P.final_flag ? P.wo[p][col] : 0.f;
    }

#pragma unroll
    for (int mt = 0; mt < 4; ++mt) {
#pragma unroll
        for (int rg = 0; rg < 4; ++rg) {
            float s = 0.f, q = 0.f;
#pragma unroll
            for (int nt = 0; nt < 6; ++nt) {
                float v = acc[mt * 6 + nt][rg] + bcol[nt];
                v = v > 0.f ? v : 0.f;
                acc[mt * 6 + nt][rg] = v;
                s += v; q += v * v;
            }
#pragma unroll
            for (int off = 1; off < 16; off <<= 1) {
                s += __shfl_xor(s, off, 64);
                q += __shfl_xor(q, off, 64);
            }
            if (ln == mt * 4 + rg) {
                rsum[wave * 64 + mt * 16 + lq * 4 + rg] = s;
                rsq [wave * 64 + mt * 16 + lq * 4 + rg] = q;
            }
        }
    }
    __syncthreads();

    float mean_[16], rstd_[16];
#pragma unroll
    for (int mt = 0; mt < 4; ++mt) {
#pragma unroll
        for (int rg = 0; rg < 4; ++rg) {
            const int row = mt * 16 + lq * 4 + rg;
            const float s = rsum[row] + rsum[64 + row] + rsum[128 + row] + rsum[192 + row];
            const float q = rsq[row] + rsq[64 + row] + rsq[128 + row] + rsq[192 + row];
            const float m = s * (1.f / 384.f);
            const float var = q * (1.f / 384.f) - m * m;
            mean_[mt * 4 + rg] = m;
            rstd_[mt * 4 + rg] = rsqrtf(var + 1e-5f);
        }
    }

    if (!P.final_flag) {
        unsigned short* hout = P.hout + (size_t)p * BTC;
#pragma unroll
        for (int mt = 0; mt < 4; ++mt)
#pragma unroll
            for (int rg = 0; rg < 4; ++rg) {
                const float m = mean_[mt * 4 + rg], rs = rstd_[mt * 4 + rg];
                const int grow = (bi << 6) + mt * 16 + lq * 4 + rg;
#pragma unroll
                for (int nt = 0; nt < 6; ++nt) {
                    const float v = (acc[mt * 6 + nt][rg] - m) * rs * gcol[nt] + becol[nt];
                    hout[(size_t)grow * C_ + nb + nt * 16 + ln] = f2bf(v);
                }
            }
    } else {
        __syncthreads();                       // rsum about to be reused
#pragma unroll
        for (int mt = 0; mt < 4; ++mt) {
#pragma unroll
            for (int rg = 0; rg < 4; ++rg) {
                const float m = mean_[mt * 4 + rg], rs = rstd_[mt * 4 + rg];
                float pr = 0.f;
#pragma unroll
                for (int nt = 0; nt < 6; ++nt)
                    pr += ((acc[mt * 6 + nt][rg] - m) * rs * gcol[nt] + becol[nt]) * wcol[nt];
#pragma unroll
                for (int off = 1; off < 16; off <<= 1)
                    pr += __shfl_xor(pr, off, 64);
                if (ln == mt * 4 + rg)
                    rsum[wave * 64 + mt * 16 + lq * 4 + rg] = pr;
            }
        }
        __syncthreads();
        if (tid < 64)
            P.pred[p][(bi << 6) + tid] =
                rsum[tid] + rsum[64 + tid] + rsum[128 + tid] + rsum[192 + tid] + P.bo[p][0];
    }
}

// w (1152,384) fp32 -> wpk fragment-major bf16:
// wpk[((r*4+wv)*6+nt)*512 + lane*8 + j] = w[(r*32 + (lane>>4)*8 + j)*384 +
//                                          wv*96 + nt*16 + (lane&15)]
__global__ __launch_bounds__(256) void pack_w_kernel(
    const float* __restrict__ s0, const float* __restrict__ s1,
    const float* __restrict__ s2, const float* __restrict__ s3,
    const float* __restrict__ s4, const float* __restrict__ s5,
    unsigned short* __restrict__ dst)
{
    const int wsel = blockIdx.y;
    const float* src = wsel == 0 ? s0 : wsel == 1 ? s1 : wsel == 2 ? s2
                     : wsel == 3 ? s3 : wsel == 4 ? s4 : s5;
    const int o = blockIdx.x * 256 + threadIdx.x;   // 442368
    const int r    = o / 12288;
    const int rem  = o - r * 12288;
    const int wv   = rem / 3072;
    const int rem2 = rem - wv * 3072;
    const int nt   = rem2 >> 9;
    const int li   = rem2 & 511;
    const int lane = li >> 3;
    const int j    = li & 7;
    const int n = wv * 96 + nt * 16 + (lane & 15);
    const int k = ((lane >> 4) << 3) + j;
    dst[(size_t)wsel * WPK1 + o] = f2bf(src[(size_t)(r * 32 + k) * C_ + n]);
}

// per-batch inclusive cumsum of duration (T=1024) + mel_len
__global__ __launch_bounds__(256) void cumsum_kernel(
    const int* __restrict__ dur, int* __restrict__ csum,
    float* __restrict__ mel_len)
{
    __shared__ int part[256];
    const int b = blockIdx.x;
    const int tid = threadIdx.x;
    int l[4];
    int s = 0;
#pragma unroll
    for (int i = 0; i < 4; ++i) { l[i] = dur[b * T_ + tid * 4 + i]; s += l[i]; }
    part[tid] = s;
    __syncthreads();
    for (int off = 1; off < 256; off <<= 1) {
        int u = 0;
        if (tid >= off) u = part[tid - off];
        __syncthreads();
        part[tid] += u;
        __syncthreads();
    }
    const int incl = part[tid];
    int run = incl - s;
#pragma unroll
    for (int i = 0; i < 4; ++i) {
        run += l[i];
        csum[b * T_ + tid * 4 + i] = run;
    }
    if (tid == 255) mel_len[b] = (float)incl;
}

// out[b,frame,:] = valid ? x[b,t,:] + pemb[pi(b,t)] + eemb[ei(b,t)] : 0  (fp32 exact)
__global__ __launch_bounds__(256) void length_reg_kernel(
    const float* __restrict__ x, const int* __restrict__ csum,
    const float* __restrict__ pbins, const float* __restrict__ pemb,
    const float* __restrict__ ptgt,
    const float* __restrict__ ebins, const float* __restrict__ eemb,
    const float* __restrict__ etgt,
    float* __restrict__ out)
{
    const int g    = blockIdx.x * 256 + threadIdx.x;  // B*2048*96
    const int c4   = g % 96;
    const int rest = g / 96;
    const int frame = rest & (MAXLEN_ - 1);
    const int b     = rest >> 11;
    const int* cr = csum + (b << 10);
    const int total = cr[T_ - 1];
    float4 v = make_float4(0.f, 0.f, 0.f, 0.f);
    if (frame < total) {
        int lo = 0, hi = T_;
        while (lo < hi) {
            const int mid = (lo + hi) >> 1;
            if (cr[mid] <= frame) lo = mid + 1; else hi = mid;
        }
        const int t = lo > T_ - 1 ? T_ - 1 : lo;
        const int row = (b << 10) + t;
        v = *(const float4*)(x + (size_t)row * C_ + c4 * 4);
        const float ptg = ptgt[row];
        int plo = 0, phi = NBINS_;
        while (plo < phi) {
            const int mid = (plo + phi) >> 1;
            if (pbins[mid] < ptg) plo = mid + 1; else phi = mid;
        }
        const float etg = etgt[row];
        int elo = 0, ehi = NBINS_;
        while (elo < ehi) {
            const int mid = (elo + ehi) >> 1;
            if (ebins[mid] < etg) elo = mid + 1; else ehi = mid;
        }
        const float4 pe = *(const float4*)(pemb + (size_t)plo * C_ + c4 * 4);
        const float4 ee = *(const float4*)(eemb + (size_t)elo * C_ + c4 * 4);
        v.x += pe.x + ee.x; v.y += pe.y + ee.y;
        v.z += pe.z + ee.z; v.w += pe.w + ee.w;
    }
    *(float4*)(out + (size_t)g * 4) = v;
}

extern "C" void kernel_launch(void* const* d_in, const int* in_sizes, int n_in,
                              void* d_out, int out_size, void* d_ws, size_t ws_size,
                              hipStream_t stream)
{
    const float* x        = (const float*)d_in[0];
    const int*   duration = (const int*)d_in[2];
    const float* P[3][10];
    for (int p = 0; p < 3; ++p)
        for (int q = 0; q < 10; ++q)
            P[p][q] = (const float*)d_in[4 + p * 10 + q];
    const float* pitch_bins    = (const float*)d_in[34];
    const float* energy_bins   = (const float*)d_in[35];
    const float* pitch_emb     = (const float*)d_in[36];
    const float* energy_emb    = (const float*)d_in[37];
    const float* pitch_target  = (const float*)d_in[38];
    const float* energy_target = (const float*)d_in[39];

    float* out_x      = (float*)d_out;                       // (B,2048,384)
    float* out_pitch  = out_x + (size_t)B_ * MAXLEN_ * C_;
    float* out_energy = out_pitch + B_ * T_;
    float* out_logdur = out_energy + B_ * T_;
    float* out_mellen = out_logdur + B_ * T_;

    // h1b (3 predictors, bf16) lives in the x_out region (75.5 MB of 100.7 MB,
    // dead before length_reg writes it)
    unsigned short* h1b = (unsigned short*)out_x;

    unsigned short* wpk = (unsigned short*)d_ws;             // 6*WPK1 bf16
    int* csum = (int*)(wpk + (size_t)6 * WPK1);

    const dim3 blk(256);

    pack_w_kernel<<<dim3(1728, 6), blk, 0, stream>>>(
        P[0][0], P[0][4], P[1][0], P[1][4], P[2][0], P[2][4], wpk);

    CvP P1;
    P1.xf = x; P1.xb = nullptr; P1.wpk = wpk;
    for (int p = 0; p < 3; ++p) {
        P1.bias[p]  = P[p][1];
        P1.gamma[p] = P[p][2];
        P1.beta[p]  = P[p][3];
        P1.wo[p]    = nullptr;
        P1.bo[p]    = nullptr;
        P1.pred[p]  = nullptr;
    }
    P1.hout = h1b;
    P1.pbins = pitch_bins; P1.pemb = pitch_emb; P1.ptgt = pitch_target;
    P1.final_flag = 0;

    CvP P2;
    P2.xf = nullptr; P2.xb = h1b; P2.wpk = wpk + (size_t)3 * WPK1;
    for (int p = 0; p < 3; ++p) {
        P2.bias[p]  = P[p][5];
        P2.gamma[p] = P[p][6];
        P2.beta[p]  = P[p][7];
        P2.wo[p]    = P[p][8];
        P2.bo[p]    = P[p][9];
    }
    P2.pred[0] = out_logdur; P2.pred[1] = out_pitch; P2.pred[2] = out_energy;
    P2.hout = nullptr;
    P2.pbins = nullptr; P2.pemb = nullptr; P2.ptgt = nullptr;
    P2.final_flag = 1;

    conv_mfma3<<<1536, blk, 0, stream>>>(P1);
    conv_mfma3<<<1536, blk, 0, stream>>>(P2);

    cumsum_kernel<<<B_, blk, 0, stream>>>(duration, csum, out_mellen);
    length_reg_kernel<<<24576, blk, 0, stream>>>(
        x, csum, pitch_bins, pitch_emb, pitch_target,
        energy_bins, energy_emb, energy_target, out_x);
}